// Round 2
// baseline (119.559 us; speedup 1.0000x reference)
//
#include <hip/hip_runtime.h>

typedef __attribute__((ext_vector_type(4))) float f32x4;
typedef __attribute__((ext_vector_type(8))) short short8;

#define N_ROWS 4096
#define KDIM   4096
#define NC     96     // padded score cols: [cls 0..19][r1 20..40][r2 41..61][pad 62..63][det 64..83][pad 84..95]
#define NSPLIT 16

__device__ inline short f2bf(float f) {
  unsigned u = __builtin_bit_cast(unsigned, f);
  u += 0x7FFFu + ((u >> 16) & 1u);   // RNE
  return (short)(u >> 16);
}

// ---------------- K0: pack weights into bf16 B-fragment order ----------------
// Wp flat index: ((K*6 + ct)*64 + l)*8 + j  for kstep K=0..127
// k-permuted so A-side lanes read CONTIGUOUS 16-float runs:
//   global k = (K>>1)*64 + (l>>4)*16 + (K&1)*8 + j
__global__ void k_pack(const float* __restrict__ Wcls, const float* __restrict__ Wr1,
                       const float* __restrict__ Wr2, const float* __restrict__ Wdet,
                       ushort* __restrict__ Wp) {
  int t = blockIdx.x * 256 + threadIdx.x;            // 0 .. 128*3072-1
  int K = t / 3072;
  int rem = t - K * 3072;
  int ct = rem >> 9;
  int rem2 = rem & 511;
  int l = rem2 >> 3;
  int j = rem2 & 7;
  int k = (K >> 1) * 64 + (l >> 4) * 16 + (K & 1) * 8 + j;
  int col = ct * 16 + (l & 15);
  float v = 0.f;
  if (col < 20)                 v = Wcls[k * 20 + col];
  else if (col < 41)            v = Wr1[k * 21 + (col - 20)];
  else if (col < 62)            v = Wr2[k * 21 + (col - 41)];
  else if (col >= 64 && col < 84) v = Wdet[k * 20 + (col - 64)];
  Wp[t] = (ushort)f2bf(v);
}

// ---------------- K1: streaming bf16 MFMA GEMM, split-K, 2-deep reg pipeline ----------------
__global__ __launch_bounds__(256, 2) void k_gemm(const float* __restrict__ roi,
    const float* __restrict__ frame, const float* __restrict__ ctx,
    const ushort* __restrict__ Wp, float* __restrict__ Spart) {
  const int lane = threadIdx.x & 63;
  const int wid = blockIdx.x * 4 + (threadIdx.x >> 6);
  const int rt = wid & 255;        // row tile (16 rows)
  const int ks = wid >> 8;         // k split 0..15 (256 k each)
  const int row = rt * 16 + (lane & 15);
  const int kg = lane >> 4;        // 0..3
  const size_t aoff = (size_t)row * KDIM + ks * 256 + kg * 16;
  const float* pr = roi   + aoff;
  const float* pf = frame + aoff;
  const float* pc = ctx   + aoff;
  const ushort* pb = Wp + (size_t)(ks * 8) * 3072 + lane * 8;

  f32x4 A[2][12];   // [buf][matrix*4 + q] ; lane's 64B contiguous per matrix per chunk
  short8 Bv[12];    // [h*6 + ct] for current chunk's 2 ksteps
  f32x4 acc[6];
#pragma unroll
  for (int i = 0; i < 6; ++i) acc[i] = (f32x4){0.f, 0.f, 0.f, 0.f};

  // prologue: issue A chunk 0
#pragma unroll
  for (int q = 0; q < 4; ++q) {
    A[0][q]     = *(const f32x4*)(pr + q * 4);
    A[0][4 + q] = *(const f32x4*)(pf + q * 4);
    A[0][8 + q] = *(const f32x4*)(pc + q * 4);
  }

#pragma unroll
  for (int c = 0; c < 4; ++c) {
    // issue B for this chunk (older than next A, so B-wait won't drain A(c+1))
#pragma unroll
    for (int h = 0; h < 2; ++h)
#pragma unroll
      for (int ct = 0; ct < 6; ++ct)
        Bv[h * 6 + ct] = *(const short8*)(pb + (size_t)(c * 2 + h) * 3072 + ct * 512);
    // issue A for next chunk
    if (c < 3) {
#pragma unroll
      for (int q = 0; q < 4; ++q) {
        A[(c + 1) & 1][q]     = *(const f32x4*)(pr + (c + 1) * 64 + q * 4);
        A[(c + 1) & 1][4 + q] = *(const f32x4*)(pf + (c + 1) * 64 + q * 4);
        A[(c + 1) & 1][8 + q] = *(const f32x4*)(pc + (c + 1) * 64 + q * 4);
      }
    }
    // convert + MFMA (2 ksteps)
#pragma unroll
    for (int h = 0; h < 2; ++h) {
      short8 aR, aD;
#pragma unroll
      for (int j = 0; j < 8; ++j) {
        const int q = h * 2 + (j >> 2), e = j & 3;
        float r = A[c & 1][q][e];
        float d = A[c & 1][4 + q][e] - A[c & 1][8 + q][e];
        aR[j] = f2bf(r);
        aD[j] = f2bf(d);
      }
#pragma unroll
      for (int ct = 0; ct < 6; ++ct)
        acc[ct] = __builtin_amdgcn_mfma_f32_16x16x32_bf16(ct < 4 ? aR : aD, Bv[h * 6 + ct], acc[ct], 0, 0, 0);
    }
  }

  float* out = Spart + (size_t)ks * (N_ROWS * NC) + (size_t)rt * 16 * NC;
  const int rbase = (lane >> 4) * 4;  // C/D: col=lane&15, row=(lane>>4)*4+reg  [m89-verified]
  const int col = lane & 15;
#pragma unroll
  for (int ct = 0; ct < 6; ++ct)
#pragma unroll
    for (int r = 0; r < 4; ++r)
      out[(size_t)(rbase + r) * NC + ct * 16 + col] = acc[ct][r];
}

// ---------------- K1.5: reduce split-K partials ----------------
__global__ void k_reduce(const float* __restrict__ Spart, float* __restrict__ S) {
  int e = blockIdx.x * 256 + threadIdx.x;
  float s = 0.f;
#pragma unroll
  for (int ks = 0; ks < NSPLIT; ++ks) s += Spart[(size_t)ks * (N_ROWS * NC) + e];
  S[e] = s;
}

// ---------------- K2: per-row softmaxes ----------------
__global__ void k_rows(const float* __restrict__ S, const float* __restrict__ bcls,
    const float* __restrict__ br1, const float* __restrict__ br2,
    float* __restrict__ clsp, float* __restrict__ rp1,
    float* __restrict__ lse1, float* __restrict__ lse2) {
  int i = blockIdx.x * 256 + threadIdx.x;
  const float* sr = S + (size_t)i * NC;
  float s[21];
  // cls_prob
  float m = -3.4e38f;
  for (int c = 0; c < 20; ++c) { s[c] = sr[c] + bcls[c]; m = fmaxf(m, s[c]); }
  float sum = 0.f;
  for (int c = 0; c < 20; ++c) { float e = expf(s[c] - m); s[c] = e; sum += e; }
  float inv = 1.f / sum;
  for (int c = 0; c < 20; ++c) clsp[(size_t)i * 20 + c] = s[c] * inv;
  // refine_prob_1 + lse1
  m = -3.4e38f;
  for (int c = 0; c < 21; ++c) { s[c] = sr[20 + c] + br1[c]; m = fmaxf(m, s[c]); }
  sum = 0.f;
  for (int c = 0; c < 21; ++c) { float e = expf(s[c] - m); s[c] = e; sum += e; }
  lse1[i] = m + logf(sum);
  inv = 1.f / sum;
  for (int c = 0; c < 21; ++c) rp1[(size_t)i * 21 + c] = s[c] * inv;
  // lse2 only
  m = -3.4e38f;
  for (int c = 0; c < 21; ++c) { s[c] = sr[41 + c] + br2[c]; m = fmaxf(m, s[c]); }
  sum = 0.f;
  for (int c = 0; c < 21; ++c) sum += expf(s[c] - m);
  lse2[i] = m + logf(sum);
}

// ---------------- K3: per-column (det softmax stats, det_cls_score, argmaxes -> seed boxes) ----------------
__global__ __launch_bounds__(256) void k_col(const float* __restrict__ S,
    const float* __restrict__ clsp, const float* __restrict__ rp1,
    const float* __restrict__ isw, const float* __restrict__ ssb,
    const float* __restrict__ bcls,
    float* __restrict__ dcs, float* __restrict__ b1out, float* __restrict__ b2out) {
  const int c = blockIdx.x;
  const int t = threadIdx.x;
  __shared__ float rv[256];
  __shared__ int ri[256];
  float m = -3.4e38f;
  for (int i = t; i < N_ROWS; i += 256) m = fmaxf(m, S[(size_t)i * NC + 64 + c]);
  rv[t] = m; __syncthreads();
  for (int o = 128; o; o >>= 1) { if (t < o) rv[t] = fmaxf(rv[t], rv[t + o]); __syncthreads(); }
  const float M = rv[0]; __syncthreads();
  float se = 0.f, scd = 0.f, v1b = -3.4e38f, v2b = -3.4e38f;
  int i1 = 0, i2 = 0;
  for (int i = t; i < N_ROWS; i += 256) {
    float w = isw[i];
    float e = expf(S[(size_t)i * NC + 64 + c] - M);
    se += e;
    scd += (S[(size_t)i * NC + c] + bcls[c]) * e;
    float v1 = clsp[(size_t)i * 20 + c] * e * w;        // argmax-equivalent to cls_prob*det_prob*ISw
    if (v1 > v1b) { v1b = v1; i1 = i; }
    float v2 = rp1[(size_t)i * 21 + c + 1] * w;          // supervision2 drops bg col
    if (v2 > v2b) { v2b = v2; i2 = i; }
  }
  rv[t] = se; __syncthreads();
  for (int o = 128; o; o >>= 1) { if (t < o) rv[t] += rv[t + o]; __syncthreads(); }
  const float SE = rv[0]; __syncthreads();
  rv[t] = scd; __syncthreads();
  for (int o = 128; o; o >>= 1) { if (t < o) rv[t] += rv[t + o]; __syncthreads(); }
  const float SCD = rv[0]; __syncthreads();
  rv[t] = v1b; ri[t] = i1; __syncthreads();
  for (int o = 128; o; o >>= 1) {
    if (t < o) { if (rv[t + o] > rv[t] || (rv[t + o] == rv[t] && ri[t + o] < ri[t])) { rv[t] = rv[t + o]; ri[t] = ri[t + o]; } }
    __syncthreads();
  }
  const int I1 = ri[0]; __syncthreads();
  rv[t] = v2b; ri[t] = i2; __syncthreads();
  for (int o = 128; o; o >>= 1) {
    if (t < o) { if (rv[t + o] > rv[t] || (rv[t + o] == rv[t] && ri[t + o] < ri[t])) { rv[t] = rv[t + o]; ri[t] = ri[t + o]; } }
    __syncthreads();
  }
  const int I2 = ri[0];
  if (t == 0) {
    dcs[c] = SCD / SE;
    for (int q = 0; q < 4; ++q) {
      b1out[c * 4 + q] = ssb[(size_t)I1 * 5 + 1 + q];
      b2out[c * 4 + q] = ssb[(size_t)I2 * 5 + 1 + q];
    }
  }
}

// ---------------- K4: per-row IoU supervision + refine-loss partials ----------------
__global__ __launch_bounds__(256) void k_sup(const float* __restrict__ S,
    const float* __restrict__ ssb, const float* __restrict__ isw,
    const int* __restrict__ label,
    const float* __restrict__ b1in, const float* __restrict__ b2in,
    const float* __restrict__ lse1, const float* __restrict__ lse2,
    const float* __restrict__ br1, const float* __restrict__ br2,
    float* __restrict__ scal) {
  __shared__ float q1[20][4], q2[20][4], a1[20], a2[20];
  __shared__ int pos[20];
  const int t = threadIdx.x;
  if (t < 20) {
    for (int q = 0; q < 4; ++q) { q1[t][q] = b1in[t * 4 + q]; q2[t][q] = b2in[t * 4 + q]; }
    a1[t] = (q1[t][2] - q1[t][0] + 1.f) * (q1[t][3] - q1[t][1] + 1.f);
    a2[t] = (q2[t][2] - q2[t][0] + 1.f) * (q2[t][3] - q2[t][1] + 1.f);
    pos[t] = (label[t] == 1);
  }
  __syncthreads();
  const int i = blockIdx.x * 256 + t;
  const float bx1 = ssb[(size_t)i * 5 + 1], by1 = ssb[(size_t)i * 5 + 2];
  const float bx2 = ssb[(size_t)i * 5 + 3], by2 = ssb[(size_t)i * 5 + 4];
  const float ab = (bx2 - bx1 + 1.f) * (by2 - by1 + 1.f);
  const float w = isw[i];
  float p1 = 0.f, n1 = 0.f, p2 = 0.f, n2 = 0.f;
  {
    float mo = -2.f; int gt = 0;
    for (int c = 0; c < 20; ++c) {
      float v = -1.f;
      if (pos[c]) {
        float xx1 = fmaxf(bx1, q1[c][0]), yy1 = fmaxf(by1, q1[c][1]);
        float xx2 = fminf(bx2, q1[c][2]), yy2 = fminf(by2, q1[c][3]);
        float iw = fmaxf(xx2 - xx1 + 1.f, 0.f), ih = fmaxf(yy2 - yy1 + 1.f, 0.f);
        float inter = iw * ih;
        v = inter / (ab + a1[c] - inter);
      }
      if (v > mo) { mo = v; gt = c; }
    }
    bool fg = mo > 0.5f;
    bool bg = (mo >= 0.1f) && (mo < 0.5f);
    if (fg || bg) {
      int col = fg ? gt + 1 : 0;
      float lp = S[(size_t)i * NC + 20 + col] + br1[col] - lse1[i];
      p1 = w * lp; n1 = 1.f;
    }
  }
  {
    float mo = -2.f; int gt = 0;
    for (int c = 0; c < 20; ++c) {
      float v = -1.f;
      if (pos[c]) {
        float xx1 = fmaxf(bx1, q2[c][0]), yy1 = fmaxf(by1, q2[c][1]);
        float xx2 = fminf(bx2, q2[c][2]), yy2 = fminf(by2, q2[c][3]);
        float iw = fmaxf(xx2 - xx1 + 1.f, 0.f), ih = fmaxf(yy2 - yy1 + 1.f, 0.f);
        float inter = iw * ih;
        v = inter / (ab + a2[c] - inter);
      }
      if (v > mo) { mo = v; gt = c; }
    }
    bool fg = mo > 0.5f;
    bool bg = (mo >= 0.1f) && (mo < 0.5f);
    if (fg || bg) {
      int col = fg ? gt + 1 : 0;
      float lp = S[(size_t)i * NC + 41 + col] + br2[col] - lse2[i];
      p2 = w * lp; n2 = 1.f;
    }
  }
  __shared__ float rs[256];
  float sums[4] = {p1, n1, p2, n2};
  float tot[4];
  for (int q = 0; q < 4; ++q) {
    rs[t] = sums[q]; __syncthreads();
    for (int o = 128; o; o >>= 1) { if (t < o) rs[t] += rs[t + o]; __syncthreads(); }
    tot[q] = rs[0]; __syncthreads();
  }
  if (t == 0) {
    atomicAdd(&scal[0], tot[0]); atomicAdd(&scal[1], tot[1]);
    atomicAdd(&scal[2], tot[2]); atomicAdd(&scal[3], tot[3]);
  }
}

// ---------------- K5: final scalar ----------------
__global__ void k_final(const float* __restrict__ dcs, const int* __restrict__ label,
                        const float* __restrict__ scal, float* __restrict__ out) {
  if (threadIdx.x == 0 && blockIdx.x == 0) {
    float cd = 0.f;
    for (int c = 0; c < 20; ++c) {
      float lab = (float)label[c];
      cd += fmaxf(1.f - lab * dcs[c], 0.f);
    }
    cd *= (1.f / 20.f);
    float rl1 = -scal[0] / scal[1];
    float rl2 = -scal[2] / scal[3];
    out[0] = cd + 0.1f * (rl1 + rl2);
  }
}

// ---------------- workspace layout (all 16B aligned) ----------------
constexpr size_t OFF_S     = 0;                               // 4096*96*4 = 1572864
constexpr size_t OFF_SCAL  = OFF_S + (size_t)N_ROWS * NC * 4; // 16
constexpr size_t OFF_DCS   = OFF_SCAL + 16;                   // 80
constexpr size_t OFF_B1    = OFF_DCS + 80;                    // 320
constexpr size_t OFF_B2    = OFF_B1 + 320;                    // 320
constexpr size_t OFF_LSE1  = OFF_B2 + 320;                    // 16384
constexpr size_t OFF_LSE2  = OFF_LSE1 + 16384;                // 16384
constexpr size_t OFF_CLSP  = OFF_LSE2 + 16384;                // 327680
constexpr size_t OFF_RP1   = OFF_CLSP + 327680;               // 344064
constexpr size_t OFF_WP    = OFF_RP1 + 344064;                // 786432
constexpr size_t OFF_SPART = OFF_WP + 786432;                 // 16*4096*96*4 = 25165824

extern "C" void kernel_launch(void* const* d_in, const int* in_sizes, int n_in,
                              void* d_out, int out_size, void* d_ws, size_t ws_size,
                              hipStream_t stream) {
  const float* roi   = (const float*)d_in[0];
  const float* ctx   = (const float*)d_in[1];
  const float* frame = (const float*)d_in[2];
  const float* Wcls  = (const float*)d_in[3];
  const float* bcls  = (const float*)d_in[4];
  const float* Wdet  = (const float*)d_in[5];
  const float* Wr1   = (const float*)d_in[7];
  const float* br1   = (const float*)d_in[8];
  const float* Wr2   = (const float*)d_in[9];
  const float* br2   = (const float*)d_in[10];
  const float* ssb   = (const float*)d_in[11];
  const float* isw   = (const float*)d_in[12];
  const int*   label = (const int*)d_in[13];

  char* ws = (char*)d_ws;
  float*  S     = (float*)(ws + OFF_S);
  float*  scal  = (float*)(ws + OFF_SCAL);
  float*  dcs   = (float*)(ws + OFF_DCS);
  float*  b1    = (float*)(ws + OFF_B1);
  float*  b2    = (float*)(ws + OFF_B2);
  float*  lse1  = (float*)(ws + OFF_LSE1);
  float*  lse2  = (float*)(ws + OFF_LSE2);
  float*  clsp  = (float*)(ws + OFF_CLSP);
  float*  rp1   = (float*)(ws + OFF_RP1);
  ushort* Wp    = (ushort*)(ws + OFF_WP);
  float*  Spart = (float*)(ws + OFF_SPART);

  hipMemsetAsync(scal, 0, 16, stream);
  k_pack<<<1536, 256, 0, stream>>>(Wcls, Wr1, Wr2, Wdet, Wp);
  k_gemm<<<1024, 256, 0, stream>>>(roi, frame, ctx, Wp, Spart);
  k_reduce<<<1536, 256, 0, stream>>>(Spart, S);
  k_rows<<<16, 256, 0, stream>>>(S, bcls, br1, br2, clsp, rp1, lse1, lse2);
  k_col<<<20, 256, 0, stream>>>(S, clsp, rp1, isw, ssb, bcls, dcs, b1, b2);
  k_sup<<<16, 256, 0, stream>>>(S, ssb, isw, label, b1, b2, lse1, lse2, br1, br2, scal);
  k_final<<<1, 64, 0, stream>>>(dcs, label, scal, (float*)d_out);
}

// Round 3
// 87.095 us; speedup vs baseline: 1.3727x; 1.3727x over previous
//
#include <hip/hip_runtime.h>

typedef __attribute__((ext_vector_type(4))) float f32x4;
typedef __attribute__((ext_vector_type(8))) short short8;

#define N_ROWS 4096
#define KDIM   4096
#define NC     96     // padded score cols: [cls 0..19][r1 20..40][r2 41..61][pad 62..63][det 64..83][pad 84..95]
#define NSPL   32     // per-wave k-splits (128 floats each)
#define NSOUT  8      // Spart splits after in-block reduction over 4 waves

__device__ inline short f2bf(float f) {
  unsigned u = __builtin_bit_cast(unsigned, f);
  u += 0x7FFFu + ((u >> 16) & 1u);   // RNE
  return (short)(u >> 16);
}

// ---------------- K0: pack weights into bf16 B-fragment order (R0-verified mapping) ----------------
// Wp flat index: ((K*6 + ct)*64 + l)*8 + j ; k = K*32 + (l>>4)*8 + j ; col = ct*16 + (l&15)
__global__ void k_pack(const float* __restrict__ Wcls, const float* __restrict__ Wr1,
                       const float* __restrict__ Wr2, const float* __restrict__ Wdet,
                       ushort* __restrict__ Wp) {
  int t = blockIdx.x * 256 + threadIdx.x;            // 0 .. 128*3072-1
  int K = t / 3072;
  int rem = t - K * 3072;
  int ct = rem >> 9;
  int rem2 = rem & 511;
  int l = rem2 >> 3;
  int j = rem2 & 7;
  int k = K * 32 + (l >> 4) * 8 + j;
  int col = ct * 16 + (l & 15);
  float v = 0.f;
  if (col < 20)                 v = Wcls[k * 20 + col];
  else if (col < 41)            v = Wr1[k * 21 + (col - 20)];
  else if (col < 62)            v = Wr2[k * 21 + (col - 41)];
  else if (col >= 64 && col < 84) v = Wdet[k * 20 + (col - 64)];
  Wp[t] = (ushort)f2bf(v);
}

// ---------------- K1: streaming bf16 MFMA GEMM, asm-pipelined loads + counted vmcnt ----------------
// All in-loop VMEM is inline asm so vmcnt counts are exact (no compiler-inserted waits).
#define GL(dst, base, OFF) \
  asm volatile("global_load_dwordx4 %0, %1, off offset:%c2" : "=v"(dst) : "v"(base), "i"(OFF) : "memory")
#define WAITV(N) asm volatile("s_waitcnt vmcnt(" #N ")" ::: "memory")
#define SB() __builtin_amdgcn_sched_barrier(0)

#define ISSUE(K) do {                                                  \
    GL(Ar[K][0], pr, (K)*128);  GL(Ar[K][1], pr, (K)*128 + 16);        \
    GL(Af[K][0], pf, (K)*128);  GL(Af[K][1], pf, (K)*128 + 16);        \
    GL(Ac[K][0], pc, (K)*128);  GL(Ac[K][1], pc, (K)*128 + 16);        \
    const ushort* pbK  = pb + (K)*3072;                                \
    const ushort* pbK2 = pbK + 2048;                                   \
    GL(Bv[K][0], pbK, 0);    GL(Bv[K][1], pbK, 1024);                  \
    GL(Bv[K][2], pbK, 2048); GL(Bv[K][3], pbK, 3072);                  \
    GL(Bv[K][4], pbK2, 0);   GL(Bv[K][5], pbK2, 1024);                 \
  } while (0)

#define COMP(K) do {                                                   \
    short8 aR, aD;                                                     \
    _Pragma("unroll")                                                  \
    for (int j = 0; j < 8; ++j) {                                      \
      const int q = j >> 2, e = j & 3;                                 \
      aR[j] = f2bf(Ar[K][q][e]);                                       \
      aD[j] = f2bf(Af[K][q][e] - Ac[K][q][e]);                         \
    }                                                                  \
    _Pragma("unroll")                                                  \
    for (int ct = 0; ct < 6; ++ct)                                     \
      acc[ct] = __builtin_amdgcn_mfma_f32_16x16x32_bf16(               \
          ct < 4 ? aR : aD, Bv[K][ct], acc[ct], 0, 0, 0);              \
  } while (0)

__global__ __launch_bounds__(256, 2) void k_gemm(const float* __restrict__ roi,
    const float* __restrict__ frame, const float* __restrict__ ctx,
    const ushort* __restrict__ Wp, float* __restrict__ Spart) {
  const int lane = threadIdx.x & 63;
  const int wid  = threadIdx.x >> 6;
  const int g    = blockIdx.x & 7;     // outer split group
  const int rt   = blockIdx.x >> 3;    // row tile (16 rows)
  const int ks   = g * 4 + wid;        // k split 0..31 (128 floats each)
  const int row  = rt * 16 + (lane & 15);
  const int kg   = lane >> 4;          // 0..3
  const size_t aoff = (size_t)row * KDIM + ks * 128 + kg * 8;
  const float* pr = roi   + aoff;
  const float* pf = frame + aoff;
  const float* pc = ctx   + aoff;
  const ushort* pb = Wp + (size_t)ks * 12288 + lane * 8;

  f32x4 Ar[4][2], Af[4][2], Ac[4][2];
  short8 Bv[4][6];
  f32x4 acc[6];
#pragma unroll
  for (int i = 0; i < 6; ++i) acc[i] = (f32x4){0.f, 0.f, 0.f, 0.f};

  ISSUE(0); ISSUE(1);
  ISSUE(2); WAITV(24); SB(); COMP(0);
  ISSUE(3); WAITV(24); SB(); COMP(1);
  WAITV(12); SB(); COMP(2);
  WAITV(0);  SB(); COMP(3);

  // in-block reduction over the 4 waves (same rows, different k) -> contiguous Spart write
  __shared__ float red[4 * 16 * NC];   // 24KB
  const int rbase = (lane >> 4) * 4;   // C/D: col=lane&15, row=(lane>>4)*4+reg  [m89-verified]
  const int col = lane & 15;
#pragma unroll
  for (int ct = 0; ct < 6; ++ct)
#pragma unroll
    for (int r = 0; r < 4; ++r)
      red[(wid * 16 + rbase + r) * NC + ct * 16 + col] = acc[ct][r];
  __syncthreads();
  const int t = threadIdx.x;
  float* outp = Spart + (size_t)g * (N_ROWS * NC) + (size_t)rt * (16 * NC);
#pragma unroll
  for (int q = 0; q < 6; ++q) {
    const int e = t * 6 + q;           // 0..1535
    outp[e] = red[e] + red[1536 + e] + red[3072 + e] + red[4608 + e];
  }
}

// ---------------- K1.5: reduce split-K partials ----------------
__global__ void k_reduce(const float* __restrict__ Spart, float* __restrict__ S) {
  int e = blockIdx.x * 256 + threadIdx.x;
  float s = 0.f;
#pragma unroll
  for (int ks = 0; ks < NSOUT; ++ks) s += Spart[(size_t)ks * (N_ROWS * NC) + e];
  S[e] = s;
}

// ---------------- K2: per-row softmaxes ----------------
__global__ void k_rows(const float* __restrict__ S, const float* __restrict__ bcls,
    const float* __restrict__ br1, const float* __restrict__ br2,
    float* __restrict__ clsp, float* __restrict__ rp1,
    float* __restrict__ lse1, float* __restrict__ lse2) {
  int i = blockIdx.x * 256 + threadIdx.x;
  const float* sr = S + (size_t)i * NC;
  float s[21];
  // cls_prob
  float m = -3.4e38f;
  for (int c = 0; c < 20; ++c) { s[c] = sr[c] + bcls[c]; m = fmaxf(m, s[c]); }
  float sum = 0.f;
  for (int c = 0; c < 20; ++c) { float e = expf(s[c] - m); s[c] = e; sum += e; }
  float inv = 1.f / sum;
  for (int c = 0; c < 20; ++c) clsp[(size_t)i * 20 + c] = s[c] * inv;
  // refine_prob_1 + lse1
  m = -3.4e38f;
  for (int c = 0; c < 21; ++c) { s[c] = sr[20 + c] + br1[c]; m = fmaxf(m, s[c]); }
  sum = 0.f;
  for (int c = 0; c < 21; ++c) { float e = expf(s[c] - m); s[c] = e; sum += e; }
  lse1[i] = m + logf(sum);
  inv = 1.f / sum;
  for (int c = 0; c < 21; ++c) rp1[(size_t)i * 21 + c] = s[c] * inv;
  // lse2 only
  m = -3.4e38f;
  for (int c = 0; c < 21; ++c) { s[c] = sr[41 + c] + br2[c]; m = fmaxf(m, s[c]); }
  sum = 0.f;
  for (int c = 0; c < 21; ++c) sum += expf(s[c] - m);
  lse2[i] = m + logf(sum);
}

// ---------------- K3: per-column (det softmax stats, det_cls_score, argmaxes -> seed boxes) ----------------
__global__ __launch_bounds__(256) void k_col(const float* __restrict__ S,
    const float* __restrict__ clsp, const float* __restrict__ rp1,
    const float* __restrict__ isw, const float* __restrict__ ssb,
    const float* __restrict__ bcls,
    float* __restrict__ dcs, float* __restrict__ b1out, float* __restrict__ b2out) {
  const int c = blockIdx.x;
  const int t = threadIdx.x;
  __shared__ float rv[256];
  __shared__ int ri[256];
  float m = -3.4e38f;
  for (int i = t; i < N_ROWS; i += 256) m = fmaxf(m, S[(size_t)i * NC + 64 + c]);
  rv[t] = m; __syncthreads();
  for (int o = 128; o; o >>= 1) { if (t < o) rv[t] = fmaxf(rv[t], rv[t + o]); __syncthreads(); }
  const float M = rv[0]; __syncthreads();
  float se = 0.f, scd = 0.f, v1b = -3.4e38f, v2b = -3.4e38f;
  int i1 = 0, i2 = 0;
  for (int i = t; i < N_ROWS; i += 256) {
    float w = isw[i];
    float e = expf(S[(size_t)i * NC + 64 + c] - M);
    se += e;
    scd += (S[(size_t)i * NC + c] + bcls[c]) * e;
    float v1 = clsp[(size_t)i * 20 + c] * e * w;        // argmax-equivalent to cls_prob*det_prob*ISw
    if (v1 > v1b) { v1b = v1; i1 = i; }
    float v2 = rp1[(size_t)i * 21 + c + 1] * w;          // supervision2 drops bg col
    if (v2 > v2b) { v2b = v2; i2 = i; }
  }
  rv[t] = se; __syncthreads();
  for (int o = 128; o; o >>= 1) { if (t < o) rv[t] += rv[t + o]; __syncthreads(); }
  const float SE = rv[0]; __syncthreads();
  rv[t] = scd; __syncthreads();
  for (int o = 128; o; o >>= 1) { if (t < o) rv[t] += rv[t + o]; __syncthreads(); }
  const float SCD = rv[0]; __syncthreads();
  rv[t] = v1b; ri[t] = i1; __syncthreads();
  for (int o = 128; o; o >>= 1) {
    if (t < o) { if (rv[t + o] > rv[t] || (rv[t + o] == rv[t] && ri[t + o] < ri[t])) { rv[t] = rv[t + o]; ri[t] = ri[t + o]; } }
    __syncthreads();
  }
  const int I1 = ri[0]; __syncthreads();
  rv[t] = v2b; ri[t] = i2; __syncthreads();
  for (int o = 128; o; o >>= 1) {
    if (t < o) { if (rv[t + o] > rv[t] || (rv[t + o] == rv[t] && ri[t + o] < ri[t])) { rv[t] = rv[t + o]; ri[t] = ri[t + o]; } }
    __syncthreads();
  }
  const int I2 = ri[0];
  if (t == 0) {
    dcs[c] = SCD / SE;
    for (int q = 0; q < 4; ++q) {
      b1out[c * 4 + q] = ssb[(size_t)I1 * 5 + 1 + q];
      b2out[c * 4 + q] = ssb[(size_t)I2 * 5 + 1 + q];
    }
  }
}

// ---------------- K4: per-row IoU supervision + refine-loss partials ----------------
__global__ __launch_bounds__(256) void k_sup(const float* __restrict__ S,
    const float* __restrict__ ssb, const float* __restrict__ isw,
    const int* __restrict__ label,
    const float* __restrict__ b1in, const float* __restrict__ b2in,
    const float* __restrict__ lse1, const float* __restrict__ lse2,
    const float* __restrict__ br1, const float* __restrict__ br2,
    float* __restrict__ scal) {
  __shared__ float q1[20][4], q2[20][4], a1[20], a2[20];
  __shared__ int pos[20];
  const int t = threadIdx.x;
  if (t < 20) {
    for (int q = 0; q < 4; ++q) { q1[t][q] = b1in[t * 4 + q]; q2[t][q] = b2in[t * 4 + q]; }
    a1[t] = (q1[t][2] - q1[t][0] + 1.f) * (q1[t][3] - q1[t][1] + 1.f);
    a2[t] = (q2[t][2] - q2[t][0] + 1.f) * (q2[t][3] - q2[t][1] + 1.f);
    pos[t] = (label[t] == 1);
  }
  __syncthreads();
  const int i = blockIdx.x * 256 + t;
  const float bx1 = ssb[(size_t)i * 5 + 1], by1 = ssb[(size_t)i * 5 + 2];
  const float bx2 = ssb[(size_t)i * 5 + 3], by2 = ssb[(size_t)i * 5 + 4];
  const float ab = (bx2 - bx1 + 1.f) * (by2 - by1 + 1.f);
  const float w = isw[i];
  float p1 = 0.f, n1 = 0.f, p2 = 0.f, n2 = 0.f;
  {
    float mo = -2.f; int gt = 0;
    for (int c = 0; c < 20; ++c) {
      float v = -1.f;
      if (pos[c]) {
        float xx1 = fmaxf(bx1, q1[c][0]), yy1 = fmaxf(by1, q1[c][1]);
        float xx2 = fminf(bx2, q1[c][2]), yy2 = fminf(by2, q1[c][3]);
        float iw = fmaxf(xx2 - xx1 + 1.f, 0.f), ih = fmaxf(yy2 - yy1 + 1.f, 0.f);
        float inter = iw * ih;
        v = inter / (ab + a1[c] - inter);
      }
      if (v > mo) { mo = v; gt = c; }
    }
    bool fg = mo > 0.5f;
    bool bg = (mo >= 0.1f) && (mo < 0.5f);
    if (fg || bg) {
      int col = fg ? gt + 1 : 0;
      float lp = S[(size_t)i * NC + 20 + col] + br1[col] - lse1[i];
      p1 = w * lp; n1 = 1.f;
    }
  }
  {
    float mo = -2.f; int gt = 0;
    for (int c = 0; c < 20; ++c) {
      float v = -1.f;
      if (pos[c]) {
        float xx1 = fmaxf(bx1, q2[c][0]), yy1 = fmaxf(by1, q2[c][1]);
        float xx2 = fminf(bx2, q2[c][2]), yy2 = fminf(by2, q2[c][3]);
        float iw = fmaxf(xx2 - xx1 + 1.f, 0.f), ih = fmaxf(yy2 - yy1 + 1.f, 0.f);
        float inter = iw * ih;
        v = inter / (ab + a2[c] - inter);
      }
      if (v > mo) { mo = v; gt = c; }
    }
    bool fg = mo > 0.5f;
    bool bg = (mo >= 0.1f) && (mo < 0.5f);
    if (fg || bg) {
      int col = fg ? gt + 1 : 0;
      float lp = S[(size_t)i * NC + 41 + col] + br2[col] - lse2[i];
      p2 = w * lp; n2 = 1.f;
    }
  }
  __shared__ float rs[256];
  float sums[4] = {p1, n1, p2, n2};
  float tot[4];
  for (int q = 0; q < 4; ++q) {
    rs[t] = sums[q]; __syncthreads();
    for (int o = 128; o; o >>= 1) { if (t < o) rs[t] += rs[t + o]; __syncthreads(); }
    tot[q] = rs[0]; __syncthreads();
  }
  if (t == 0) {
    atomicAdd(&scal[0], tot[0]); atomicAdd(&scal[1], tot[1]);
    atomicAdd(&scal[2], tot[2]); atomicAdd(&scal[3], tot[3]);
  }
}

// ---------------- K5: final scalar ----------------
__global__ void k_final(const float* __restrict__ dcs, const int* __restrict__ label,
                        const float* __restrict__ scal, float* __restrict__ out) {
  if (threadIdx.x == 0 && blockIdx.x == 0) {
    float cd = 0.f;
    for (int c = 0; c < 20; ++c) {
      float lab = (float)label[c];
      cd += fmaxf(1.f - lab * dcs[c], 0.f);
    }
    cd *= (1.f / 20.f);
    float rl1 = -scal[0] / scal[1];
    float rl2 = -scal[2] / scal[3];
    out[0] = cd + 0.1f * (rl1 + rl2);
  }
}

// ---------------- workspace layout (all 16B aligned) ----------------
constexpr size_t OFF_S     = 0;                               // 4096*96*4 = 1572864
constexpr size_t OFF_SCAL  = OFF_S + (size_t)N_ROWS * NC * 4; // 16
constexpr size_t OFF_DCS   = OFF_SCAL + 16;                   // 80
constexpr size_t OFF_B1    = OFF_DCS + 80;                    // 320
constexpr size_t OFF_B2    = OFF_B1 + 320;                    // 320
constexpr size_t OFF_LSE1  = OFF_B2 + 320;                    // 16384
constexpr size_t OFF_LSE2  = OFF_LSE1 + 16384;                // 16384
constexpr size_t OFF_CLSP  = OFF_LSE2 + 16384;                // 327680
constexpr size_t OFF_RP1   = OFF_CLSP + 327680;               // 344064
constexpr size_t OFF_WP    = OFF_RP1 + 344064;                // 786432
constexpr size_t OFF_SPART = OFF_WP + 786432;                 // 8*4096*96*4 = 12582912

extern "C" void kernel_launch(void* const* d_in, const int* in_sizes, int n_in,
                              void* d_out, int out_size, void* d_ws, size_t ws_size,
                              hipStream_t stream) {
  const float* roi   = (const float*)d_in[0];
  const float* ctx   = (const float*)d_in[1];
  const float* frame = (const float*)d_in[2];
  const float* Wcls  = (const float*)d_in[3];
  const float* bcls  = (const float*)d_in[4];
  const float* Wdet  = (const float*)d_in[5];
  const float* Wr1   = (const float*)d_in[7];
  const float* br1   = (const float*)d_in[8];
  const float* Wr2   = (const float*)d_in[9];
  const float* br2   = (const float*)d_in[10];
  const float* ssb   = (const float*)d_in[11];
  const float* isw   = (const float*)d_in[12];
  const int*   label = (const int*)d_in[13];

  char* ws = (char*)d_ws;
  float*  S     = (float*)(ws + OFF_S);
  float*  scal  = (float*)(ws + OFF_SCAL);
  float*  dcs   = (float*)(ws + OFF_DCS);
  float*  b1    = (float*)(ws + OFF_B1);
  float*  b2    = (float*)(ws + OFF_B2);
  float*  lse1  = (float*)(ws + OFF_LSE1);
  float*  lse2  = (float*)(ws + OFF_LSE2);
  float*  clsp  = (float*)(ws + OFF_CLSP);
  float*  rp1   = (float*)(ws + OFF_RP1);
  ushort* Wp    = (ushort*)(ws + OFF_WP);
  float*  Spart = (float*)(ws + OFF_SPART);

  hipMemsetAsync(scal, 0, 16, stream);
  k_pack<<<1536, 256, 0, stream>>>(Wcls, Wr1, Wr2, Wdet, Wp);
  k_gemm<<<2048, 256, 0, stream>>>(roi, frame, ctx, Wp, Spart);
  k_reduce<<<1536, 256, 0, stream>>>(Spart, S);
  k_rows<<<16, 256, 0, stream>>>(S, bcls, br1, br2, clsp, rp1, lse1, lse2);
  k_col<<<20, 256, 0, stream>>>(S, clsp, rp1, isw, ssb, bcls, dcs, b1, b2);
  k_sup<<<16, 256, 0, stream>>>(S, ssb, isw, label, b1, b2, lse1, lse2, br1, br2, scal);
  k_final<<<1, 64, 0, stream>>>(dcs, label, scal, (float*)d_out);
}